// Round 5
// baseline (148.943 us; speedup 1.0000x reference)
//
#include <hip/hip_runtime.h>

// BiPointNet: 3x (binarized 1x1 conv + BN batch-stats + ReLU) + maxpool over K.
// 262144 positions; channels 64->64->64->128. Popcount-GEMM on 64-bit masks.
// v5: k1 rewritten for MLP: 4096 blocks, 4 outstanding float4 loads per wave
// issued before processing (load->ballot chain was 1-deep before: 39us -> BW).

typedef unsigned long long u64;

#define P_TOTAL (8192 * 32)

__device__ __forceinline__ u64 bcast64(u64 x, int p) {
    unsigned lo = __builtin_amdgcn_readlane((unsigned)x, p);
    unsigned hi = __builtin_amdgcn_readlane((unsigned)(x >> 32), p);
    return ((u64)hi << 32) | lo;
}

// BN(batch stats)+scale+gamma+beta folded to v = a*dot + b for channel c
__device__ __forceinline__ void affine_from_stats(const int* __restrict__ sd,
        const int* __restrict__ sq, const float* __restrict__ scale,
        const float* __restrict__ gamma, const float* __restrict__ beta,
        int c, float& a, float& b) {
    const double invN = 1.0 / (double)P_TOTAL;
    double m = (double)sd[c] * invN;
    double var = (double)sq[c] * invN - m * m;
    double sc = (double)scale[c];
    double inv = 1.0 / sqrt(sc * sc * var + 1e-5);
    double g = (double)gamma[c];
    a = (float)(g * inv * sc);
    b = (float)((double)beta[c] - g * inv * sc * m);
}

// integer threshold T s.t. fmaf(a,(float)d,b)>0  <=>  d' >= T, where d' = dot
// (flip=false) or d' = -dot (flip=true). Exact: candidates verified by fmaf.
__device__ __forceinline__ int make_thresh(float a, float b, bool& flip) {
    if (a == 0.f) { flip = false; return (b > 0.f) ? -65 : 65; }
    double r = -(double)b / (double)a;
    r = fmin(fmax(r, -1e6), 1e6);
    int t0 = (int)floor(r);
    int T;
    if (a > 0.f) {
        flip = false;
        T = t0 + 2;
        if (fmaf(a, (float)(t0 + 1), b) > 0.f) T = t0 + 1;
        if (fmaf(a, (float)(t0    ), b) > 0.f) T = t0;
        if (fmaf(a, (float)(t0 - 1), b) > 0.f) T = t0 - 1;
    } else {
        flip = true;
        int H = t0 - 2;
        if (fmaf(a, (float)(t0 - 1), b) > 0.f) H = t0 - 1;
        if (fmaf(a, (float)(t0    ), b) > 0.f) H = t0;
        if (fmaf(a, (float)(t0 + 1), b) > 0.f) H = t0 + 1;
        T = -H;
    }
    return max(-65, min(65, T));
}

// ---------------- K0: pack weights into bitmasks, zero stats ----------------
// W1 packed with the k1 ballot permutation: channel c -> bit (c&3)*16 + (c>>2)
__global__ void k0_pack(const float* __restrict__ W1, const float* __restrict__ W2,
                        const float* __restrict__ W3,
                        ulonglong2* __restrict__ wp1, ulonglong2* __restrict__ wp2,
                        ulonglong2* __restrict__ wp3, int* __restrict__ stats) {
    int t = threadIdx.x;
    stats[t] = 0;
    stats[t + 256] = 0;
    if (t < 64) {
        u64 s = 0, nz = 0;
        for (int c = 0; c < 64; ++c) {
            float w = W1[t * 64 + c];
            int p = ((c & 3) << 4) | (c >> 2);
            if (w > 0.f) s |= 1ull << p;
            if (w != 0.f) nz |= 1ull << p;
        }
        wp1[t] = make_ulonglong2(s, nz);
    } else if (t < 128) {
        int o = t - 64;
        u64 pos = 0, neg = 0;
        for (int c = 0; c < 64; ++c) {
            float w = W2[o * 64 + c];
            if (w > 0.f) pos |= 1ull << c;
            if (w < 0.f) neg |= 1ull << c;
        }
        wp2[o] = make_ulonglong2(pos, neg);
    } else {
        int o = t - 128;
        u64 pos = 0, neg = 0;
        for (int c = 0; c < 64; ++c) {
            float w = W3[o * 64 + c];
            if (w > 0.f) pos |= 1ull << c;
            if (w < 0.f) neg |= 1ull << c;
        }
        wp3[o] = make_ulonglong2(pos, neg);
    }
}

// ------------- K1: MLP-4 input pack (ballots) + layer-1 dot stats -----------
__global__ void __launch_bounds__(256) k1_pack_stats(
    const float4* __restrict__ in4, const ulonglong2* __restrict__ wp1,
    ulonglong2* __restrict__ A1, int* __restrict__ sd_g, int* __restrict__ sq_g) {
    const int lane = threadIdx.x & 63;
    const int wib = threadIdx.x >> 6;
    const int wid = (blockIdx.x << 2) | wib;       // 16384 waves x 16 positions
    const ulonglong2 w = wp1[lane];                // permuted sign / nonzero
    const int sh = (lane >> 4) << 4;
    const size_t base = (size_t)wid * 256 + lane;  // 16 pos * 16 float4/pos

    // issue all 4 loads before touching any result: 4 outstanding 1KB loads
    float4 v0 = in4[base];
    float4 v1 = in4[base + 64];
    float4 v2 = in4[base + 128];
    float4 v3 = in4[base + 192];

    int sd = 0, sq = 0;
    auto proc = [&](float4 v, int q0) {
        u64 bs0 = __ballot(v.x > 0.f), bn0 = __ballot(v.x != 0.f);
        u64 bs1 = __ballot(v.y > 0.f), bn1 = __ballot(v.y != 0.f);
        u64 bs2 = __ballot(v.z > 0.f), bn2 = __ballot(v.z != 0.f);
        u64 bs3 = __ballot(v.w > 0.f), bn3 = __ballot(v.w != 0.f);
        u64 myS = ((bs0 >> sh) & 0xFFFFull) | (((bs1 >> sh) & 0xFFFFull) << 16)
                | (((bs2 >> sh) & 0xFFFFull) << 32) | (((bs3 >> sh) & 0xFFFFull) << 48);
        u64 myN = ((bn0 >> sh) & 0xFFFFull) | (((bn1 >> sh) & 0xFFFFull) << 16)
                | (((bn2 >> sh) & 0xFFFFull) << 32) | (((bn3 >> sh) & 0xFFFFull) << 48);
        if ((lane & 15) == 0) A1[q0 + (lane >> 4)] = make_ulonglong2(myS, myN);
        #pragma unroll
        for (int p = 0; p < 4; ++p) {              // wave-uniform (SALU) masks
            const int s2 = p << 4;
            u64 as = ((bs0 >> s2) & 0xFFFFull) | (((bs1 >> s2) & 0xFFFFull) << 16)
                   | (((bs2 >> s2) & 0xFFFFull) << 32) | (((bs3 >> s2) & 0xFFFFull) << 48);
            u64 an = ((bn0 >> s2) & 0xFFFFull) | (((bn1 >> s2) & 0xFFFFull) << 16)
                   | (((bn2 >> s2) & 0xFFFFull) << 32) | (((bn3 >> s2) & 0xFFFFull) << 48);
            u64 mnz = an & w.y;
            int dot = __popcll(mnz) - 2 * __popcll(mnz & (as ^ w.x));
            sd += dot; sq += dot * dot;
        }
    };
    const int q_base = wid * 16;
    proc(v0, q_base);
    proc(v1, q_base + 4);
    proc(v2, q_base + 8);
    proc(v3, q_base + 12);

    __shared__ int rd[4][64], rq[4][64];
    rd[wib][lane] = sd; rq[wib][lane] = sq;
    __syncthreads();
    if (threadIdx.x < 64) {
        atomicAdd(&sd_g[lane], rd[0][lane] + rd[1][lane] + rd[2][lane] + rd[3][lane]);
        atomicAdd(&sq_g[lane], rq[0][lane] + rq[1][lane] + rq[2][lane] + rq[3][lane]);
    }
}

// -------- K2: layer-1 binarize (int thresh) -> A2, layer-2 dot stats --------
__global__ void __launch_bounds__(256, 4) k2_bin1_stats2(
    const ulonglong2* __restrict__ A1, const ulonglong2* __restrict__ wp1,
    const ulonglong2* __restrict__ wp2, const int* __restrict__ s1d,
    const int* __restrict__ s1q, const float* __restrict__ scale,
    const float* __restrict__ gamma, const float* __restrict__ beta,
    u64* __restrict__ A2, int* __restrict__ sd_g, int* __restrict__ sq_g) {
    const int lane = threadIdx.x & 63;
    const int wib = threadIdx.x >> 6;
    const int wid = (blockIdx.x << 2) | wib;       // 4096 waves x 64 positions
    float a, b;
    affine_from_stats(s1d, s1q, scale, gamma, beta, lane, a, b);
    bool flip;
    const int T = make_thresh(a, b, flip);
    ulonglong2 w1 = wp1[lane];
    const u64 w1S = flip ? ~w1.x : w1.x;           // flip => dot' = -dot
    const u64 w1N = w1.y;
    const ulonglong2 w2 = wp2[lane];               // natural orientation (stats)

    const int q0 = wid * 64;
    const ulonglong2 aa = A1[q0 + lane];           // coalesced 16B/lane
    u64 mymask = 0;
    int sd = 0, sq = 0;
    #pragma unroll 8
    for (int p = 0; p < 64; ++p) {
        u64 as = bcast64(aa.x, p);
        u64 an = bcast64(aa.y, p);
        u64 mnz = an & w1N;
        int dot1 = __popcll(mnz) - 2 * __popcll(mnz & (as ^ w1S));
        u64 A = __ballot(dot1 >= T);
        mymask = (lane == p) ? A : mymask;
        int d2 = __popcll(A & w2.x) - __popcll(A & w2.y);
        sd += d2; sq += d2 * d2;
    }
    A2[q0 + lane] = mymask;                        // coalesced 8B/lane

    __shared__ int rd[4][64], rq[4][64];
    rd[wib][lane] = sd; rq[wib][lane] = sq;
    __syncthreads();
    if (threadIdx.x < 64) {
        atomicAdd(&sd_g[lane], rd[0][lane] + rd[1][lane] + rd[2][lane] + rd[3][lane]);
        atomicAdd(&sq_g[lane], rq[0][lane] + rq[1][lane] + rq[2][lane] + rq[3][lane]);
    }
}

// -- K3: layer-2 binarize (int thresh), layer-3 dots -> stats + row max/min --
__global__ void __launch_bounds__(256, 4) k3_bin2_stats3(
    const u64* __restrict__ A2, const ulonglong2* __restrict__ wp2,
    const ulonglong2* __restrict__ wp3, const int* __restrict__ s2d,
    const int* __restrict__ s2q, const float* __restrict__ scale,
    const float* __restrict__ gamma, const float* __restrict__ beta,
    short* __restrict__ dmm, int* __restrict__ sd_g, int* __restrict__ sq_g) {
    const int lane = threadIdx.x & 63;
    const int wib = threadIdx.x >> 6;
    const int wid = (blockIdx.x << 2) | wib;       // 4096 waves x 64 pos (2 rows)
    float a, b;
    affine_from_stats(s2d, s2q, scale, gamma, beta, lane, a, b);
    bool flip;
    const int T = make_thresh(a, b, flip);
    const ulonglong2 w2 = wp2[lane];
    const u64 w2P = flip ? w2.y : w2.x;            // flip => swap pos/neg
    const u64 w2N = flip ? w2.x : w2.y;
    const ulonglong2 w3a = wp3[lane];
    const ulonglong2 w3b = wp3[lane + 64];

    const int q0 = wid * 64;
    const u64 aa = A2[q0 + lane];                  // coalesced 8B/lane
    int sda = 0, sqa = 0, sdb = 0, sqb = 0;
    #pragma unroll
    for (int r = 0; r < 2; ++r) {
        int maxa = -127, mina = 127, maxb = -127, minb = 127;
        #pragma unroll 8
        for (int pp = 0; pp < 32; ++pp) {
            const int p = (r << 5) | pp;
            u64 A = bcast64(aa, p);
            int d2 = __popcll(A & w2P) - __popcll(A & w2N);
            u64 A3 = __ballot(d2 >= T);
            int da = __popcll(A3 & w3a.x) - __popcll(A3 & w3a.y);
            int db = __popcll(A3 & w3b.x) - __popcll(A3 & w3b.y);
            sda += da; sqa += da * da; sdb += db; sqb += db * db;
            maxa = max(maxa, da); mina = min(mina, da);
            maxb = max(maxb, db); minb = min(minb, db);
        }
        const int m = (q0 >> 5) + r;
        dmm[m * 128 + lane]      = (short)((maxa & 0xFF) | ((mina & 0xFF) << 8));
        dmm[m * 128 + 64 + lane] = (short)((maxb & 0xFF) | ((minb & 0xFF) << 8));
    }
    __shared__ int rda[4][64], rqa[4][64], rdb[4][64], rqb[4][64];
    rda[wib][lane] = sda; rqa[wib][lane] = sqa;
    rdb[wib][lane] = sdb; rqb[wib][lane] = sqb;
    __syncthreads();
    if (threadIdx.x < 64) {
        atomicAdd(&sd_g[lane],      rda[0][lane] + rda[1][lane] + rda[2][lane] + rda[3][lane]);
        atomicAdd(&sq_g[lane],      rqa[0][lane] + rqa[1][lane] + rqa[2][lane] + rqa[3][lane]);
        atomicAdd(&sd_g[lane + 64], rdb[0][lane] + rdb[1][lane] + rdb[2][lane] + rdb[3][lane]);
        atomicAdd(&sq_g[lane + 64], rqb[0][lane] + rqb[1][lane] + rqb[2][lane] + rqb[3][lane]);
    }
}

// -------- K4: v = a*(a>=0?dmax:dmin)+b, ReLU, write [8192,128] --------------
__global__ void __launch_bounds__(256) k4_out(
    const short* __restrict__ dmm, const int* __restrict__ s3d,
    const int* __restrict__ s3q, const float* __restrict__ scale,
    const float* __restrict__ gamma, const float* __restrict__ beta,
    float* __restrict__ out) {
    __shared__ float sa[128], sb[128];
    if (threadIdx.x < 128)
        affine_from_stats(s3d, s3q, scale, gamma, beta, threadIdx.x,
                          sa[threadIdx.x], sb[threadIdx.x]);
    __syncthreads();
    const int idx = blockIdx.x * 256 + threadIdx.x;   // m*128 + o
    const int o = idx & 127;
    short pk = dmm[idx];
    int mx = (signed char)(pk & 0xFF);
    int mn = (signed char)((pk >> 8) & 0xFF);
    float a = sa[o], b = sb[o];
    float v = fmaf(a, (float)(a >= 0.f ? mx : mn), b);
    out[idx] = fmaxf(v, 0.f);
}

extern "C" void kernel_launch(void* const* d_in, const int* in_sizes, int n_in,
                              void* d_out, int out_size, void* d_ws, size_t ws_size,
                              hipStream_t stream) {
    const float* agg = (const float*)d_in[0];
    const float* W1 = (const float*)d_in[1];
    const float* s1 = (const float*)d_in[2];
    const float* g1 = (const float*)d_in[3];
    const float* b1 = (const float*)d_in[4];
    const float* W2 = (const float*)d_in[5];
    const float* s2 = (const float*)d_in[6];
    const float* g2 = (const float*)d_in[7];
    const float* b2 = (const float*)d_in[8];
    const float* W3 = (const float*)d_in[9];
    const float* s3 = (const float*)d_in[10];
    const float* g3 = (const float*)d_in[11];
    const float* b3 = (const float*)d_in[12];
    float* out = (float*)d_out;

    char* ws = (char*)d_ws;
    ulonglong2* wp1 = (ulonglong2*)(ws + 0);
    ulonglong2* wp2 = (ulonglong2*)(ws + 1024);
    ulonglong2* wp3 = (ulonglong2*)(ws + 2048);
    int* stats = (int*)(ws + 4096);                                    // 512 ints
    ulonglong2* A1 = (ulonglong2*)(ws + 8192);                         // 4 MB
    u64* A2 = (u64*)(ws + 8192 + (size_t)P_TOTAL * 16);                // 2 MB
    short* dmm = (short*)(ws + 8192 + (size_t)P_TOTAL * 24);           // 2 MB

    int* s1d = stats;        int* s1q = stats + 64;
    int* s2d = stats + 128;  int* s2q = stats + 192;
    int* s3d = stats + 256;  int* s3q = stats + 384;

    k0_pack<<<1, 256, 0, stream>>>(W1, W2, W3, wp1, wp2, wp3, stats);
    k1_pack_stats<<<4096, 256, 0, stream>>>((const float4*)agg, wp1, A1, s1d, s1q);
    k2_bin1_stats2<<<1024, 256, 0, stream>>>(A1, wp1, wp2, s1d, s1q, s1, g1, b1, A2, s2d, s2q);
    k3_bin2_stats3<<<1024, 256, 0, stream>>>(A2, wp2, wp3, s2d, s2q, s2, g2, b2, dmm, s3d, s3q);
    k4_out<<<4096, 256, 0, stream>>>(dmm, s3d, s3q, s3, g3, b3, out);
}

// Round 6
// 74.295 us; speedup vs baseline: 2.0047x; 2.0047x over previous
//
#include <hip/hip_runtime.h>

// BiPointNet: 3x (binarized 1x1 conv + BN batch-stats + ReLU) + maxpool over K.
// 262144 positions; channels 64->64->64->128. Popcount-GEMM on 64-bit masks.
// v6: stats atomics de-contended: 16 replicas (distinct cache lines) and
// (sd,sq) packed into ONE u64 atomicAdd (sq<2^31 so no cross-field carry;
// sd exact via mod-2^32 two's complement). k1: 8 loads in flight per wave.

typedef unsigned long long u64;

#define P_TOTAL (8192 * 32)
#define NREP 16

__device__ __forceinline__ u64 bcast64(u64 x, int p) {
    unsigned lo = __builtin_amdgcn_readlane((unsigned)x, p);
    unsigned hi = __builtin_amdgcn_readlane((unsigned)(x >> 32), p);
    return ((u64)hi << 32) | lo;
}

__device__ __forceinline__ u64 pack_stats(int sd, int sq) {
    return ((u64)(unsigned)sd << 32) | (u64)(unsigned)sq;
}

// sum 16 replicas of packed stats, fold BN+scale+gamma+beta -> v = a*dot + b
__device__ __forceinline__ void affine_from_stats(const u64* __restrict__ st,
        int c, const float* __restrict__ scale, const float* __restrict__ gamma,
        const float* __restrict__ beta, int cparam, float& a, float& b) {
    u64 v = 0;
    #pragma unroll
    for (int r = 0; r < NREP; ++r) v += st[r * 256 + c];
    int sd = (int)(v >> 32);
    int sq = (int)(unsigned)(v & 0xFFFFFFFFull);
    const double invN = 1.0 / (double)P_TOTAL;
    double m = (double)sd * invN;
    double var = (double)sq * invN - m * m;
    double sc = (double)scale[cparam];
    double inv = 1.0 / sqrt(sc * sc * var + 1e-5);
    double g = (double)gamma[cparam];
    a = (float)(g * inv * sc);
    b = (float)((double)beta[cparam] - g * inv * sc * m);
}

// integer threshold T s.t. fmaf(a,(float)d,b)>0  <=>  d' >= T, where d' = dot
// (flip=false) or d' = -dot (flip=true). Exact: candidates verified by fmaf.
__device__ __forceinline__ int make_thresh(float a, float b, bool& flip) {
    if (a == 0.f) { flip = false; return (b > 0.f) ? -65 : 65; }
    double r = -(double)b / (double)a;
    r = fmin(fmax(r, -1e6), 1e6);
    int t0 = (int)floor(r);
    int T;
    if (a > 0.f) {
        flip = false;
        T = t0 + 2;
        if (fmaf(a, (float)(t0 + 1), b) > 0.f) T = t0 + 1;
        if (fmaf(a, (float)(t0    ), b) > 0.f) T = t0;
        if (fmaf(a, (float)(t0 - 1), b) > 0.f) T = t0 - 1;
    } else {
        flip = true;
        int H = t0 - 2;
        if (fmaf(a, (float)(t0 - 1), b) > 0.f) H = t0 - 1;
        if (fmaf(a, (float)(t0    ), b) > 0.f) H = t0;
        if (fmaf(a, (float)(t0 + 1), b) > 0.f) H = t0 + 1;
        T = -H;
    }
    return max(-65, min(65, T));
}

// ---------------- K0: pack weights into bitmasks, zero stats ----------------
// W1 packed with the k1 ballot permutation: channel c -> bit (c&3)*16 + (c>>2)
__global__ void k0_pack(const float* __restrict__ W1, const float* __restrict__ W2,
                        const float* __restrict__ W3,
                        ulonglong2* __restrict__ wp1, ulonglong2* __restrict__ wp2,
                        ulonglong2* __restrict__ wp3, u64* __restrict__ stats) {
    int t = threadIdx.x;
    #pragma unroll
    for (int r = 0; r < NREP; ++r) stats[r * 256 + t] = 0;
    if (t < 64) {
        u64 s = 0, nz = 0;
        for (int c = 0; c < 64; ++c) {
            float w = W1[t * 64 + c];
            int p = ((c & 3) << 4) | (c >> 2);
            if (w > 0.f) s |= 1ull << p;
            if (w != 0.f) nz |= 1ull << p;
        }
        wp1[t] = make_ulonglong2(s, nz);
    } else if (t < 128) {
        int o = t - 64;
        u64 pos = 0, neg = 0;
        for (int c = 0; c < 64; ++c) {
            float w = W2[o * 64 + c];
            if (w > 0.f) pos |= 1ull << c;
            if (w < 0.f) neg |= 1ull << c;
        }
        wp2[o] = make_ulonglong2(pos, neg);
    } else {
        int o = t - 128;
        u64 pos = 0, neg = 0;
        for (int c = 0; c < 64; ++c) {
            float w = W3[o * 64 + c];
            if (w > 0.f) pos |= 1ull << c;
            if (w < 0.f) neg |= 1ull << c;
        }
        wp3[o] = make_ulonglong2(pos, neg);
    }
}

// ------------- K1: input pack (ballots) + layer-1 dot stats -----------------
// 2048 blocks, 8192 waves x 32 positions; all 8 float4 loads issued up front.
__global__ void __launch_bounds__(256) k1_pack_stats(
    const float4* __restrict__ in4, const ulonglong2* __restrict__ wp1,
    ulonglong2* __restrict__ A1, u64* __restrict__ stats) {
    const int lane = threadIdx.x & 63;
    const int wib = threadIdx.x >> 6;
    const int wid = (blockIdx.x << 2) | wib;
    const ulonglong2 w = wp1[lane];                // permuted sign / nonzero
    const int sh = (lane >> 4) << 4;
    const size_t base = (size_t)wid * 512 + lane;  // 32 pos * 16 float4/pos

    float4 v0 = in4[base];
    float4 v1 = in4[base + 64];
    float4 v2 = in4[base + 128];
    float4 v3 = in4[base + 192];
    float4 v4 = in4[base + 256];
    float4 v5 = in4[base + 320];
    float4 v6 = in4[base + 384];
    float4 v7 = in4[base + 448];

    int sd = 0, sq = 0;
    auto proc = [&](float4 v, int q0) {
        u64 bs0 = __ballot(v.x > 0.f), bn0 = __ballot(v.x != 0.f);
        u64 bs1 = __ballot(v.y > 0.f), bn1 = __ballot(v.y != 0.f);
        u64 bs2 = __ballot(v.z > 0.f), bn2 = __ballot(v.z != 0.f);
        u64 bs3 = __ballot(v.w > 0.f), bn3 = __ballot(v.w != 0.f);
        u64 myS = ((bs0 >> sh) & 0xFFFFull) | (((bs1 >> sh) & 0xFFFFull) << 16)
                | (((bs2 >> sh) & 0xFFFFull) << 32) | (((bs3 >> sh) & 0xFFFFull) << 48);
        u64 myN = ((bn0 >> sh) & 0xFFFFull) | (((bn1 >> sh) & 0xFFFFull) << 16)
                | (((bn2 >> sh) & 0xFFFFull) << 32) | (((bn3 >> sh) & 0xFFFFull) << 48);
        if ((lane & 15) == 0) A1[q0 + (lane >> 4)] = make_ulonglong2(myS, myN);
        #pragma unroll
        for (int p = 0; p < 4; ++p) {              // wave-uniform (SALU) masks
            const int s2 = p << 4;
            u64 as = ((bs0 >> s2) & 0xFFFFull) | (((bs1 >> s2) & 0xFFFFull) << 16)
                   | (((bs2 >> s2) & 0xFFFFull) << 32) | (((bs3 >> s2) & 0xFFFFull) << 48);
            u64 an = ((bn0 >> s2) & 0xFFFFull) | (((bn1 >> s2) & 0xFFFFull) << 16)
                   | (((bn2 >> s2) & 0xFFFFull) << 32) | (((bn3 >> s2) & 0xFFFFull) << 48);
            u64 mnz = an & w.y;
            int dot = __popcll(mnz) - 2 * __popcll(mnz & (as ^ w.x));
            sd += dot; sq += dot * dot;
        }
    };
    const int q_base = wid * 32;
    proc(v0, q_base);      proc(v1, q_base + 4);
    proc(v2, q_base + 8);  proc(v3, q_base + 12);
    proc(v4, q_base + 16); proc(v5, q_base + 20);
    proc(v6, q_base + 24); proc(v7, q_base + 28);

    __shared__ int rd[4][64], rq[4][64];
    rd[wib][lane] = sd; rq[wib][lane] = sq;
    __syncthreads();
    if (threadIdx.x < 64) {
        int td = rd[0][lane] + rd[1][lane] + rd[2][lane] + rd[3][lane];
        int tq = rq[0][lane] + rq[1][lane] + rq[2][lane] + rq[3][lane];
        atomicAdd(&stats[(blockIdx.x & (NREP - 1)) * 256 + lane], pack_stats(td, tq));
    }
}

// -------- K2: layer-1 binarize (int thresh) -> A2, layer-2 dot stats --------
__global__ void __launch_bounds__(256, 4) k2_bin1_stats2(
    const ulonglong2* __restrict__ A1, const ulonglong2* __restrict__ wp1,
    const ulonglong2* __restrict__ wp2, const float* __restrict__ scale,
    const float* __restrict__ gamma, const float* __restrict__ beta,
    u64* __restrict__ A2, u64* __restrict__ stats) {
    const int lane = threadIdx.x & 63;
    const int wib = threadIdx.x >> 6;
    const int wid = (blockIdx.x << 2) | wib;       // 4096 waves x 64 positions
    float a, b;
    affine_from_stats(stats, lane, scale, gamma, beta, lane, a, b);
    bool flip;
    const int T = make_thresh(a, b, flip);
    ulonglong2 w1 = wp1[lane];
    const u64 w1S = flip ? ~w1.x : w1.x;           // flip => dot' = -dot
    const u64 w1N = w1.y;
    const ulonglong2 w2 = wp2[lane];               // natural orientation (stats)

    const int q0 = wid * 64;
    const ulonglong2 aa = A1[q0 + lane];           // coalesced 16B/lane
    u64 mymask = 0;
    int sd = 0, sq = 0;
    #pragma unroll 8
    for (int p = 0; p < 64; ++p) {
        u64 as = bcast64(aa.x, p);
        u64 an = bcast64(aa.y, p);
        u64 mnz = an & w1N;
        int dot1 = __popcll(mnz) - 2 * __popcll(mnz & (as ^ w1S));
        u64 A = __ballot(dot1 >= T);
        mymask = (lane == p) ? A : mymask;
        int d2 = __popcll(A & w2.x) - __popcll(A & w2.y);
        sd += d2; sq += d2 * d2;
    }
    A2[q0 + lane] = mymask;                        // coalesced 8B/lane

    __shared__ int rd[4][64], rq[4][64];
    rd[wib][lane] = sd; rq[wib][lane] = sq;
    __syncthreads();
    if (threadIdx.x < 64) {
        int td = rd[0][lane] + rd[1][lane] + rd[2][lane] + rd[3][lane];
        int tq = rq[0][lane] + rq[1][lane] + rq[2][lane] + rq[3][lane];
        atomicAdd(&stats[(blockIdx.x & (NREP - 1)) * 256 + 64 + lane], pack_stats(td, tq));
    }
}

// -- K3: layer-2 binarize (int thresh), layer-3 dots -> stats + row max/min --
__global__ void __launch_bounds__(256, 4) k3_bin2_stats3(
    const u64* __restrict__ A2, const ulonglong2* __restrict__ wp2,
    const ulonglong2* __restrict__ wp3, const float* __restrict__ scale,
    const float* __restrict__ gamma, const float* __restrict__ beta,
    short* __restrict__ dmm, u64* __restrict__ stats) {
    const int lane = threadIdx.x & 63;
    const int wib = threadIdx.x >> 6;
    const int wid = (blockIdx.x << 2) | wib;       // 4096 waves x 64 pos (2 rows)
    float a, b;
    affine_from_stats(stats, 64 + lane, scale, gamma, beta, lane, a, b);
    bool flip;
    const int T = make_thresh(a, b, flip);
    const ulonglong2 w2 = wp2[lane];
    const u64 w2P = flip ? w2.y : w2.x;            // flip => swap pos/neg
    const u64 w2N = flip ? w2.x : w2.y;
    const ulonglong2 w3a = wp3[lane];
    const ulonglong2 w3b = wp3[lane + 64];

    const int q0 = wid * 64;
    const u64 aa = A2[q0 + lane];                  // coalesced 8B/lane
    int sda = 0, sqa = 0, sdb = 0, sqb = 0;
    #pragma unroll
    for (int r = 0; r < 2; ++r) {
        int maxa = -127, mina = 127, maxb = -127, minb = 127;
        #pragma unroll 8
        for (int pp = 0; pp < 32; ++pp) {
            const int p = (r << 5) | pp;
            u64 A = bcast64(aa, p);
            int d2 = __popcll(A & w2P) - __popcll(A & w2N);
            u64 A3 = __ballot(d2 >= T);
            int da = __popcll(A3 & w3a.x) - __popcll(A3 & w3a.y);
            int db = __popcll(A3 & w3b.x) - __popcll(A3 & w3b.y);
            sda += da; sqa += da * da; sdb += db; sqb += db * db;
            maxa = max(maxa, da); mina = min(mina, da);
            maxb = max(maxb, db); minb = min(minb, db);
        }
        const int m = (q0 >> 5) + r;
        dmm[m * 128 + lane]      = (short)((maxa & 0xFF) | ((mina & 0xFF) << 8));
        dmm[m * 128 + 64 + lane] = (short)((maxb & 0xFF) | ((minb & 0xFF) << 8));
    }
    __shared__ int rda[4][64], rqa[4][64], rdb[4][64], rqb[4][64];
    rda[wib][lane] = sda; rqa[wib][lane] = sqa;
    rdb[wib][lane] = sdb; rqb[wib][lane] = sqb;
    __syncthreads();
    if (threadIdx.x < 64) {
        const int rep = (blockIdx.x & (NREP - 1)) * 256;
        int tda = rda[0][lane] + rda[1][lane] + rda[2][lane] + rda[3][lane];
        int tqa = rqa[0][lane] + rqa[1][lane] + rqa[2][lane] + rqa[3][lane];
        int tdb = rdb[0][lane] + rdb[1][lane] + rdb[2][lane] + rdb[3][lane];
        int tqb = rqb[0][lane] + rqb[1][lane] + rqb[2][lane] + rqb[3][lane];
        atomicAdd(&stats[rep + 128 + lane], pack_stats(tda, tqa));
        atomicAdd(&stats[rep + 192 + lane], pack_stats(tdb, tqb));
    }
}

// -------- K4: v = a*(a>=0?dmax:dmin)+b, ReLU, write [8192,128] --------------
__global__ void __launch_bounds__(256) k4_out(
    const short* __restrict__ dmm, const float* __restrict__ scale,
    const float* __restrict__ gamma, const float* __restrict__ beta,
    const u64* __restrict__ stats, float* __restrict__ out) {
    __shared__ float sa[128], sb[128];
    if (threadIdx.x < 128)
        affine_from_stats(stats, 128 + threadIdx.x, scale, gamma, beta,
                          threadIdx.x, sa[threadIdx.x], sb[threadIdx.x]);
    __syncthreads();
    const int idx = blockIdx.x * 256 + threadIdx.x;   // m*128 + o
    const int o = idx & 127;
    short pk = dmm[idx];
    int mx = (signed char)(pk & 0xFF);
    int mn = (signed char)((pk >> 8) & 0xFF);
    float a = sa[o], b = sb[o];
    float v = fmaf(a, (float)(a >= 0.f ? mx : mn), b);
    out[idx] = fmaxf(v, 0.f);
}

extern "C" void kernel_launch(void* const* d_in, const int* in_sizes, int n_in,
                              void* d_out, int out_size, void* d_ws, size_t ws_size,
                              hipStream_t stream) {
    const float* agg = (const float*)d_in[0];
    const float* W1 = (const float*)d_in[1];
    const float* s1 = (const float*)d_in[2];
    const float* g1 = (const float*)d_in[3];
    const float* b1 = (const float*)d_in[4];
    const float* W2 = (const float*)d_in[5];
    const float* s2 = (const float*)d_in[6];
    const float* g2 = (const float*)d_in[7];
    const float* b2 = (const float*)d_in[8];
    const float* W3 = (const float*)d_in[9];
    const float* s3 = (const float*)d_in[10];
    const float* g3 = (const float*)d_in[11];
    const float* b3 = (const float*)d_in[12];
    float* out = (float*)d_out;

    char* ws = (char*)d_ws;
    ulonglong2* wp1 = (ulonglong2*)(ws + 0);               // 1 KB
    ulonglong2* wp2 = (ulonglong2*)(ws + 1024);            // 1 KB
    ulonglong2* wp3 = (ulonglong2*)(ws + 2048);            // 2 KB
    u64* stats = (u64*)(ws + 4096);                        // 16 reps x 256 u64 = 32 KB
    ulonglong2* A1 = (ulonglong2*)(ws + 65536);                             // 4 MB
    u64* A2 = (u64*)(ws + 65536 + (size_t)P_TOTAL * 16);                    // 2 MB
    short* dmm = (short*)(ws + 65536 + (size_t)P_TOTAL * 24);               // 2 MB

    k0_pack<<<1, 256, 0, stream>>>(W1, W2, W3, wp1, wp2, wp3, stats);
    k1_pack_stats<<<2048, 256, 0, stream>>>((const float4*)agg, wp1, A1, stats);
    k2_bin1_stats2<<<1024, 256, 0, stream>>>(A1, wp1, wp2, s1, g1, b1, A2, stats);
    k3_bin2_stats3<<<1024, 256, 0, stream>>>(A2, wp2, wp3, s2, g2, b2, dmm, stats);
    k4_out<<<4096, 256, 0, stream>>>(dmm, s3, g3, b3, stats, out);
}

// Round 7
// 72.176 us; speedup vs baseline: 2.0636x; 1.0294x over previous
//
#include <hip/hip_runtime.h>

// BiPointNet: 3x (binarized 1x1 conv + BN batch-stats + ReLU) + maxpool over K.
// 262144 positions; channels 64->64->64->128. Popcount-GEMM on 64-bit masks.
// v7: k2/k3 at 8 waves/SIMD (2048 blocks, 32 pos/wave), per-BLOCK BN-param
// preamble in LDS, k0 parallel per-row weight pack (no serial ballot chains).

typedef unsigned long long u64;
typedef unsigned int u32;

#define P_TOTAL (8192 * 32)
#define NREP 16

__device__ __forceinline__ u64 bcast64(u64 x, int p) {
    unsigned lo = __builtin_amdgcn_readlane((unsigned)x, p);
    unsigned hi = __builtin_amdgcn_readlane((unsigned)(x >> 32), p);
    return ((u64)hi << 32) | lo;
}

__device__ __forceinline__ u64 pack_stats(int sd, int sq) {
    return ((u64)(unsigned)sd << 32) | (u64)(unsigned)sq;
}

// sum NREP replicas of packed stats, fold BN+scale+gamma+beta -> v = a*dot + b
__device__ __forceinline__ void affine_from_stats(const u64* __restrict__ st,
        int c, const float* __restrict__ scale, const float* __restrict__ gamma,
        const float* __restrict__ beta, int cparam, float& a, float& b) {
    u64 v = 0;
    #pragma unroll
    for (int r = 0; r < NREP; ++r) v += st[r * 256 + c];
    int sd = (int)(v >> 32);
    int sq = (int)(unsigned)(v & 0xFFFFFFFFull);
    const double invN = 1.0 / (double)P_TOTAL;
    double m = (double)sd * invN;
    double var = (double)sq * invN - m * m;
    double sc = (double)scale[cparam];
    double inv = 1.0 / sqrt(sc * sc * var + 1e-5);
    double g = (double)gamma[cparam];
    a = (float)(g * inv * sc);
    b = (float)((double)beta[cparam] - g * inv * sc * m);
}

// integer threshold T s.t. fmaf(a,(float)d,b)>0  <=>  d' >= T, where d' = dot
// (flip=false) or d' = -dot (flip=true). Exact: candidates verified by fmaf.
__device__ __forceinline__ int make_thresh(float a, float b, bool& flip) {
    if (a == 0.f) { flip = false; return (b > 0.f) ? -65 : 65; }
    double r = -(double)b / (double)a;
    r = fmin(fmax(r, -1e6), 1e6);
    int t0 = (int)floor(r);
    int T;
    if (a > 0.f) {
        flip = false;
        T = t0 + 2;
        if (fmaf(a, (float)(t0 + 1), b) > 0.f) T = t0 + 1;
        if (fmaf(a, (float)(t0    ), b) > 0.f) T = t0;
        if (fmaf(a, (float)(t0 - 1), b) > 0.f) T = t0 - 1;
    } else {
        flip = true;
        int H = t0 - 2;
        if (fmaf(a, (float)(t0 - 1), b) > 0.f) H = t0 - 1;
        if (fmaf(a, (float)(t0    ), b) > 0.f) H = t0;
        if (fmaf(a, (float)(t0 + 1), b) > 0.f) H = t0 + 1;
        T = -H;
    }
    return max(-65, min(65, T));
}

// block preamble: thread t<64 computes channel t's (T, flip) into LDS
__device__ __forceinline__ void block_params(const u64* __restrict__ stats,
        int stat_off, const float* __restrict__ scale, const float* __restrict__ gamma,
        const float* __restrict__ beta, int* gT, int* gF) {
    const int t = threadIdx.x;
    if (t < 64) {
        float a, b;
        affine_from_stats(stats, stat_off + t, scale, gamma, beta, t, a, b);
        bool flip;
        gT[t] = make_thresh(a, b, flip);
        gF[t] = flip ? 1 : 0;
    }
    __syncthreads();
}

// ---------------- K0: pack weights (one thread per output row) --------------
// W1 packed with the k1 ballot permutation: channel c -> bit (c&3)*16 + (c>>2)
__global__ void __launch_bounds__(256) k0_pack(
    const float* __restrict__ W1, const float* __restrict__ W2,
    const float* __restrict__ W3, ulonglong2* __restrict__ wp1,
    ulonglong2* __restrict__ wp2, ulonglong2* __restrict__ wp3,
    u64* __restrict__ stats) {
    const int t = threadIdx.x;
    #pragma unroll
    for (int r = 0; r < NREP; ++r) stats[r * 256 + t] = 0;

    const float* src;
    ulonglong2* dst;
    bool perm, l1;
    if (t < 64)       { src = W1 + t * 64;         dst = wp1 + t;         perm = true;  l1 = true;  }
    else if (t < 128) { src = W2 + (t - 64) * 64;  dst = wp2 + (t - 64);  perm = false; l1 = false; }
    else              { src = W3 + (t - 128) * 64; dst = wp3 + (t - 128); perm = false; l1 = false; }

    const float4* s4 = (const float4*)src;
    float4 v[16];
    #pragma unroll
    for (int j = 0; j < 16; ++j) v[j] = s4[j];   // 16 independent loads

    u64 hiM = 0, loM = 0;
    #pragma unroll
    for (int j = 0; j < 16; ++j) {
        const float e0 = v[j].x, e1 = v[j].y, e2 = v[j].z, e3 = v[j].w;
        #pragma unroll
        for (int k = 0; k < 4; ++k) {
            const float w = (k == 0) ? e0 : (k == 1) ? e1 : (k == 2) ? e2 : e3;
            const int c = 4 * j + k;
            const int p = perm ? (((c & 3) << 4) | (c >> 2)) : c;
            const bool bh = (w > 0.f);
            const bool bl = l1 ? (w != 0.f) : (w < 0.f);
            if (bh) hiM |= 1ull << p;
            if (bl) loM |= 1ull << p;
        }
    }
    *dst = make_ulonglong2(hiM, loM);   // (sign,nz) for L1; (pos,neg) for L2/L3
}

// ------------- K1: input pack (ballots) + layer-1 dot stats -----------------
// 2048 blocks, 8192 waves x 32 positions; all 8 float4 loads issued up front.
__global__ void __launch_bounds__(256) k1_pack_stats(
    const float4* __restrict__ in4, const ulonglong2* __restrict__ wp1,
    ulonglong2* __restrict__ A1, u64* __restrict__ stats) {
    const int lane = threadIdx.x & 63;
    const int wib = threadIdx.x >> 6;
    const int wid = (blockIdx.x << 2) | wib;
    const ulonglong2 w = wp1[lane];                // permuted sign / nonzero
    const int sh = (lane >> 4) << 4;
    const size_t base = (size_t)wid * 512 + lane;  // 32 pos * 16 float4/pos

    float4 v0 = in4[base];
    float4 v1 = in4[base + 64];
    float4 v2 = in4[base + 128];
    float4 v3 = in4[base + 192];
    float4 v4 = in4[base + 256];
    float4 v5 = in4[base + 320];
    float4 v6 = in4[base + 384];
    float4 v7 = in4[base + 448];

    int sd = 0, sq = 0;
    auto proc = [&](float4 v, int q0) {
        u64 bs0 = __ballot(v.x > 0.f), bn0 = __ballot(v.x != 0.f);
        u64 bs1 = __ballot(v.y > 0.f), bn1 = __ballot(v.y != 0.f);
        u64 bs2 = __ballot(v.z > 0.f), bn2 = __ballot(v.z != 0.f);
        u64 bs3 = __ballot(v.w > 0.f), bn3 = __ballot(v.w != 0.f);
        u64 myS = ((bs0 >> sh) & 0xFFFFull) | (((bs1 >> sh) & 0xFFFFull) << 16)
                | (((bs2 >> sh) & 0xFFFFull) << 32) | (((bs3 >> sh) & 0xFFFFull) << 48);
        u64 myN = ((bn0 >> sh) & 0xFFFFull) | (((bn1 >> sh) & 0xFFFFull) << 16)
                | (((bn2 >> sh) & 0xFFFFull) << 32) | (((bn3 >> sh) & 0xFFFFull) << 48);
        if ((lane & 15) == 0) A1[q0 + (lane >> 4)] = make_ulonglong2(myS, myN);
        #pragma unroll
        for (int p = 0; p < 4; ++p) {              // wave-uniform (SALU) masks
            const int s2 = p << 4;
            u64 as = ((bs0 >> s2) & 0xFFFFull) | (((bs1 >> s2) & 0xFFFFull) << 16)
                   | (((bs2 >> s2) & 0xFFFFull) << 32) | (((bs3 >> s2) & 0xFFFFull) << 48);
            u64 an = ((bn0 >> s2) & 0xFFFFull) | (((bn1 >> s2) & 0xFFFFull) << 16)
                   | (((bn2 >> s2) & 0xFFFFull) << 32) | (((bn3 >> s2) & 0xFFFFull) << 48);
            u64 mnz = an & w.y;
            int dot = __popcll(mnz) - 2 * __popcll(mnz & (as ^ w.x));
            sd += dot; sq += dot * dot;
        }
    };
    const int q_base = wid * 32;
    proc(v0, q_base);      proc(v1, q_base + 4);
    proc(v2, q_base + 8);  proc(v3, q_base + 12);
    proc(v4, q_base + 16); proc(v5, q_base + 20);
    proc(v6, q_base + 24); proc(v7, q_base + 28);

    __shared__ int rd[4][64], rq[4][64];
    rd[wib][lane] = sd; rq[wib][lane] = sq;
    __syncthreads();
    if (threadIdx.x < 64) {
        int td = rd[0][lane] + rd[1][lane] + rd[2][lane] + rd[3][lane];
        int tq = rq[0][lane] + rq[1][lane] + rq[2][lane] + rq[3][lane];
        atomicAdd(&stats[(blockIdx.x & (NREP - 1)) * 256 + lane], pack_stats(td, tq));
    }
}

// -------- K2: layer-1 binarize (int thresh) -> A2, layer-2 dot stats --------
// 2048 blocks, 8192 waves x 32 positions (per-lane u64 halves of A1).
__global__ void __launch_bounds__(256) k2_bin1_stats2(
    const ulonglong2* __restrict__ A1, const ulonglong2* __restrict__ wp1,
    const ulonglong2* __restrict__ wp2, const float* __restrict__ scale,
    const float* __restrict__ gamma, const float* __restrict__ beta,
    u64* __restrict__ A2, u64* __restrict__ stats) {
    __shared__ int gT[64], gF[64];
    block_params(stats, 0, scale, gamma, beta, gT, gF);

    const int lane = threadIdx.x & 63;
    const int wib = threadIdx.x >> 6;
    const int wid = (blockIdx.x << 2) | wib;       // 8192 waves x 32 positions
    const int T = gT[lane];
    const bool flip = gF[lane] != 0;
    ulonglong2 w1 = wp1[lane];
    const u64 w1S = flip ? ~w1.x : w1.x;           // flip => dot' = -dot
    const u64 w1N = w1.y;
    const ulonglong2 w2 = wp2[lane];               // natural orientation (stats)

    const u64 av = ((const u64*)A1)[(size_t)wid * 64 + lane];   // 32 pos x 2 u64
    u64 mymask = 0;
    int sd = 0, sq = 0;
    #pragma unroll 8
    for (int p = 0; p < 32; ++p) {
        u64 as = bcast64(av, 2 * p);
        u64 an = bcast64(av, 2 * p + 1);
        u64 mnz = an & w1N;
        int dot1 = __popcll(mnz) - 2 * __popcll(mnz & (as ^ w1S));
        u64 A = __ballot(dot1 >= T);
        if (lane == p) mymask = A;
        int d2 = __popcll(A & w2.x) - __popcll(A & w2.y);
        sd += d2; sq += d2 * d2;
    }
    if (lane < 32) A2[(size_t)wid * 32 + lane] = mymask;   // 256B contiguous

    __shared__ int rd[4][64], rq[4][64];
    rd[wib][lane] = sd; rq[wib][lane] = sq;
    __syncthreads();
    if (threadIdx.x < 64) {
        int td = rd[0][lane] + rd[1][lane] + rd[2][lane] + rd[3][lane];
        int tq = rq[0][lane] + rq[1][lane] + rq[2][lane] + rq[3][lane];
        atomicAdd(&stats[(blockIdx.x & (NREP - 1)) * 256 + 64 + lane], pack_stats(td, tq));
    }
}

// -- K3: layer-2 binarize (int thresh), layer-3 dots -> stats + row max/min --
// 2048 blocks, 8192 waves x 32 positions = exactly one output row per wave.
__global__ void __launch_bounds__(256) k3_bin2_stats3(
    const u64* __restrict__ A2, const ulonglong2* __restrict__ wp2,
    const ulonglong2* __restrict__ wp3, const float* __restrict__ scale,
    const float* __restrict__ gamma, const float* __restrict__ beta,
    short* __restrict__ dmm, u64* __restrict__ stats) {
    __shared__ int gT[64], gF[64];
    block_params(stats, 64, scale, gamma, beta, gT, gF);

    const int lane = threadIdx.x & 63;
    const int wib = threadIdx.x >> 6;
    const int wid = (blockIdx.x << 2) | wib;       // row m = wid
    const int T = gT[lane];
    const bool flip = gF[lane] != 0;
    const ulonglong2 w2 = wp2[lane];
    const u64 w2P = flip ? w2.y : w2.x;            // flip => swap pos/neg
    const u64 w2N = flip ? w2.x : w2.y;
    const ulonglong2 w3a = wp3[lane];
    const ulonglong2 w3b = wp3[lane + 64];

    const u32 a32 = ((const u32*)A2)[(size_t)wid * 64 + lane];  // 32 pos x 2 u32
    int sda = 0, sqa = 0, sdb = 0, sqb = 0;
    int maxa = -127, mina = 127, maxb = -127, minb = 127;
    #pragma unroll 8
    for (int p = 0; p < 32; ++p) {
        u32 lo = __builtin_amdgcn_readlane(a32, 2 * p);
        u32 hi = __builtin_amdgcn_readlane(a32, 2 * p + 1);
        u64 A = ((u64)hi << 32) | lo;
        int d2 = __popcll(A & w2P) - __popcll(A & w2N);
        u64 A3 = __ballot(d2 >= T);
        int da = __popcll(A3 & w3a.x) - __popcll(A3 & w3a.y);
        int db = __popcll(A3 & w3b.x) - __popcll(A3 & w3b.y);
        sda += da; sqa += da * da; sdb += db; sqb += db * db;
        maxa = max(maxa, da); mina = min(mina, da);
        maxb = max(maxb, db); minb = min(minb, db);
    }
    dmm[wid * 128 + lane]      = (short)((maxa & 0xFF) | ((mina & 0xFF) << 8));
    dmm[wid * 128 + 64 + lane] = (short)((maxb & 0xFF) | ((minb & 0xFF) << 8));

    __shared__ int rda[4][64], rqa[4][64], rdb[4][64], rqb[4][64];
    rda[wib][lane] = sda; rqa[wib][lane] = sqa;
    rdb[wib][lane] = sdb; rqb[wib][lane] = sqb;
    __syncthreads();
    if (threadIdx.x < 64) {
        const int rep = (blockIdx.x & (NREP - 1)) * 256;
        int tda = rda[0][lane] + rda[1][lane] + rda[2][lane] + rda[3][lane];
        int tqa = rqa[0][lane] + rqa[1][lane] + rqa[2][lane] + rqa[3][lane];
        int tdb = rdb[0][lane] + rdb[1][lane] + rdb[2][lane] + rdb[3][lane];
        int tqb = rqb[0][lane] + rqb[1][lane] + rqb[2][lane] + rqb[3][lane];
        atomicAdd(&stats[rep + 128 + lane], pack_stats(tda, tqa));
        atomicAdd(&stats[rep + 192 + lane], pack_stats(tdb, tqb));
    }
}

// -------- K4: v = a*(a>=0?dmax:dmin)+b, ReLU, write [8192,128] --------------
__global__ void __launch_bounds__(512) k4_out(
    const short* __restrict__ dmm, const float* __restrict__ scale,
    const float* __restrict__ gamma, const float* __restrict__ beta,
    const u64* __restrict__ stats, float* __restrict__ out) {
    __shared__ float sa[128], sb[128];
    if (threadIdx.x < 128)
        affine_from_stats(stats, 128 + threadIdx.x, scale, gamma, beta,
                          threadIdx.x, sa[threadIdx.x], sb[threadIdx.x]);
    __syncthreads();
    const int idx = blockIdx.x * 512 + threadIdx.x;   // m*128 + o
    const int o = idx & 127;
    short pk = dmm[idx];
    int mx = (signed char)(pk & 0xFF);
    int mn = (signed char)((pk >> 8) & 0xFF);
    float a = sa[o], b = sb[o];
    float v = fmaf(a, (float)(a >= 0.f ? mx : mn), b);
    out[idx] = fmaxf(v, 0.f);
}

extern "C" void kernel_launch(void* const* d_in, const int* in_sizes, int n_in,
                              void* d_out, int out_size, void* d_ws, size_t ws_size,
                              hipStream_t stream) {
    const float* agg = (const float*)d_in[0];
    const float* W1 = (const float*)d_in[1];
    const float* s1 = (const float*)d_in[2];
    const float* g1 = (const float*)d_in[3];
    const float* b1 = (const float*)d_in[4];
    const float* W2 = (const float*)d_in[5];
    const float* s2 = (const float*)d_in[6];
    const float* g2 = (const float*)d_in[7];
    const float* b2 = (const float*)d_in[8];
    const float* W3 = (const float*)d_in[9];
    const float* s3 = (const float*)d_in[10];
    const float* g3 = (const float*)d_in[11];
    const float* b3 = (const float*)d_in[12];
    float* out = (float*)d_out;

    char* ws = (char*)d_ws;
    ulonglong2* wp1 = (ulonglong2*)(ws + 0);               // 1 KB
    ulonglong2* wp2 = (ulonglong2*)(ws + 1024);            // 1 KB
    ulonglong2* wp3 = (ulonglong2*)(ws + 2048);            // 2 KB
    u64* stats = (u64*)(ws + 4096);                        // 16 reps x 256 u64 = 32 KB
    ulonglong2* A1 = (ulonglong2*)(ws + 65536);                             // 4 MB
    u64* A2 = (u64*)(ws + 65536 + (size_t)P_TOTAL * 16);                    // 2 MB
    short* dmm = (short*)(ws + 65536 + (size_t)P_TOTAL * 24);               // 2 MB

    k0_pack<<<1, 256, 0, stream>>>(W1, W2, W3, wp1, wp2, wp3, stats);
    k1_pack_stats<<<2048, 256, 0, stream>>>((const float4*)agg, wp1, A1, stats);
    k2_bin1_stats2<<<2048, 256, 0, stream>>>(A1, wp1, wp2, s1, g1, b1, A2, stats);
    k3_bin2_stats3<<<2048, 256, 0, stream>>>(A2, wp2, wp3, s2, g2, b2, dmm, stats);
    k4_out<<<2048, 512, 0, stream>>>(dmm, s3, g3, b3, stats, out);
}